// Round 14
// baseline (78.560 us; speedup 1.0000x reference)
//
#include <hip/hip_runtime.h>
#include <math.h>

#define BB 256
#define VV 4096
#define DD 64
#define NCHUNK 32
#define CHB 8192    // chunk bytes: 32 rows x 64 d x 4 B

typedef __attribute__((ext_vector_type(8))) _Float16 f16x8;
typedef __attribute__((ext_vector_type(2))) __fp16 fp16x2;   // cvt_pkrtz return type
typedef __attribute__((ext_vector_type(4))) float f32x4;
typedef __attribute__((address_space(3))) void lds_void_t;
typedef const __attribute__((address_space(1))) void gvoid_t;

// ---------------------------------------------------------------------------
// Kernel 1: 1024 blocks of 256 thr (4 waves): block = (a, v-quarter).
// r13 cycle-accounting: per-chunk period ~= SUM of mem+LDS+VALU+MFMA, i.e.
// nothing overlaps at 2 waves/SIMD (160KB LDS forced 1 block/CU). Fix:
// 32KB-LDS blocks -> 4 blocks/CU = 4 waves/SIMD, 4 independent barrier
// domains; phases of different blocks overlap each other's memory waits.
// Per block: 1024 rows in 32 chunks of 32 rows; 4 LDS buffers, depth-2
// counted vmcnt(4), one raw s_barrier per chunk. Wave cg owns cols
// [64cg,64cg+64) exclusively -> direct partial stores (no intra-block merge).
// ---------------------------------------------------------------------------
__global__ __launch_bounds__(256) void topk_sim_kernel(
    const float* __restrict__ F, const float* __restrict__ lan,
    float* __restrict__ max0P, float* __restrict__ max1P)
{
  extern __shared__ __align__(16) char smem[];   // 4 x 8KB chunk buffers

  const int t = threadIdx.x;
  const int a       = blockIdx.x >> 2;
  const int quarter = blockIdx.x & 3;
  const int wave = t >> 6;       // = cg in [0,4)
  const int lane = t & 63;
  const int cl = lane & 15;      // row (A) / col (B/C) within 16x16 tile
  const int o  = lane >> 4;      // k-octet group
  const int cg = wave;           // col quarter

  const char* gFa = (const char*)(F + (size_t)a * VV * DD
                                  + (size_t)quarter * 1024 * DD);

  // ---- B fragments (loads+cvt fully complete before any staging DMA,
  //      so in-loop vmcnt counts only DMA instructions) ----
  f16x8 bf[4][2];
#pragma unroll
  for (int ct = 0; ct < 4; ++ct)
#pragma unroll
    for (int s = 0; s < 2; ++s) {
      const float* p = lan + (cg * 64 + ct * 16 + cl) * DD + s * 32 + o * 8;
      float4 u0 = *(const float4*)p, u1 = *(const float4*)(p + 4);
      union { f16x8 v; fp16x2 h[4]; } U;
      U.h[0] = __builtin_amdgcn_cvt_pkrtz(u0.x, u0.y);
      U.h[1] = __builtin_amdgcn_cvt_pkrtz(u0.z, u0.w);
      U.h[2] = __builtin_amdgcn_cvt_pkrtz(u1.x, u1.y);
      U.h[3] = __builtin_amdgcn_cvt_pkrtz(u1.z, u1.w);
      bf[ct][s] = U.v;
    }

  // pre-swizzled per-lane global source offsets (G21: linear LDS dest,
  // inverse-swizzled source, swizzled read). Wave stages rows [8w, 8w+8).
  int soff[2];
#pragma unroll
  for (int i = 0; i < 2; ++i) {
    int row = wave * 8 + i * 4 + o;              // row in [0,32)
    soff[i] = row * 256 + (cl ^ (row & 7)) * 16;
  }

  auto stage = [&](int ch, char* buf) {
    const char* g = gFa + (size_t)ch * CHB;
    char* dst = buf + wave * 2048;               // wave-uniform base
#pragma unroll
    for (int i = 0; i < 2; ++i) {
      __builtin_amdgcn_global_load_lds(
          (gvoid_t*)(g + soff[i]),
          (lds_void_t*)(dst + i * 1024), 16, 0, 0);
    }
  };

  // ---- prologue: stage chunks 0,1 (4 DMAs in flight) ----
  stage(0, smem);
  stage(1, smem + CHB);

  float m0[4], m1[4];
#pragma unroll
  for (int ct = 0; ct < 4; ++ct) { m0[ct] = -INFINITY; m1[ct] = -INFINITY; }

  auto compute = [&](const char* buf) {
#pragma unroll
    for (int rt = 0; rt < 2; ++rt) {
      const int row = rt * 16 + cl;              // all 32 rows of the chunk
      const int rx = row & 7;
      const char* rp = buf + row * 256;
      float4 u00 = *(const float4*)(rp + ((((o * 2 + 0) ^ rx)) << 4));
      float4 u01 = *(const float4*)(rp + ((((o * 2 + 1) ^ rx)) << 4));
      float4 u10 = *(const float4*)(rp + ((8 + ((o * 2 + 0) ^ rx)) << 4));
      float4 u11 = *(const float4*)(rp + ((8 + ((o * 2 + 1) ^ rx)) << 4));
      union { f16x8 v; fp16x2 h[4]; } A0, A1;
      A0.h[0] = __builtin_amdgcn_cvt_pkrtz(u00.x, u00.y);
      A0.h[1] = __builtin_amdgcn_cvt_pkrtz(u00.z, u00.w);
      A0.h[2] = __builtin_amdgcn_cvt_pkrtz(u01.x, u01.y);
      A0.h[3] = __builtin_amdgcn_cvt_pkrtz(u01.z, u01.w);
      A1.h[0] = __builtin_amdgcn_cvt_pkrtz(u10.x, u10.y);
      A1.h[1] = __builtin_amdgcn_cvt_pkrtz(u10.z, u10.w);
      A1.h[2] = __builtin_amdgcn_cvt_pkrtz(u11.x, u11.y);
      A1.h[3] = __builtin_amdgcn_cvt_pkrtz(u11.z, u11.w);
#pragma unroll
      for (int ct = 0; ct < 4; ++ct) {
        f32x4 acc = {0.f, 0.f, 0.f, 0.f};
        acc = __builtin_amdgcn_mfma_f32_16x16x32_f16(A0.v, bf[ct][0], acc, 0, 0, 0);
        acc = __builtin_amdgcn_mfma_f32_16x16x32_f16(A1.v, bf[ct][1], acc, 0, 0, 0);
        float h1 = fmaxf(acc[0], acc[1]), q1 = fminf(acc[0], acc[1]);
        float h2 = fmaxf(acc[2], acc[3]), q2 = fminf(acc[2], acc[3]);
        float M0 = fmaxf(h1, h2);
        float M1 = fmaxf(fminf(h1, h2), fmaxf(q1, q2));
        float old0 = m0[ct];
        m0[ct] = fmaxf(old0, M0);
        m1[ct] = fmaxf(m1[ct], fmaxf(fminf(old0, M0), M1));
      }
    }
  };

  // ---- main loop: depth-2 counted-vmcnt pipeline, 1 raw barrier/chunk ----
#pragma unroll 1
  for (int ch = 0; ch < NCHUNK; ++ch) {
    if (ch + 2 < NCHUNK) {
      stage(ch + 2, smem + (size_t)((ch + 2) & 3) * CHB);
      asm volatile("s_waitcnt vmcnt(4)" ::: "memory");   // my ch loads done
    } else if (ch + 1 < NCHUNK) {
      asm volatile("s_waitcnt vmcnt(2)" ::: "memory");
    } else {
      asm volatile("s_waitcnt vmcnt(0)" ::: "memory");
    }
    __builtin_amdgcn_s_barrier();            // everyone's ch loads done
    __builtin_amdgcn_sched_barrier(0);
    compute(smem + (size_t)(ch & 3) * CHB);
  }

  // ---- merge across the 4 k-octet row-groups; store per-wave partials ----
#pragma unroll
  for (int ct = 0; ct < 4; ++ct) {
#pragma unroll
    for (int off = 16; off <= 32; off <<= 1) {
      float p0 = __shfl_xor(m0[ct], off);
      float p1 = __shfl_xor(m1[ct], off);
      float n1 = fmaxf(fminf(m0[ct], p0), fmaxf(m1[ct], p1));
      m0[ct] = fmaxf(m0[ct], p0);
      m1[ct] = n1;
    }
    if (lane < 16) {
      const int col = cg * 64 + ct * 16 + lane;
      max0P[((size_t)a * 4 + quarter) * BB + col] = m0[ct];
      max1P[((size_t)a * 4 + quarter) * BB + col] = m1[ct];
    }
  }
}

// ---------------------------------------------------------------------------
// Kernel 2: per row b, merge the 4 v-quarter partials per a, LSE over 511
// logits, loss_b = LSE - diag.
// ---------------------------------------------------------------------------
__global__ __launch_bounds__(256) void lse_kernel(
    const float* __restrict__ max0P, const float* __restrict__ max1P,
    float* __restrict__ lossb)
{
  __shared__ float red[256];
  __shared__ float diag;
  const int b = blockIdx.x;
  const int t = threadIdx.x;     // t = a
  float M0 = -INFINITY, M1 = -INFINITY;
#pragma unroll
  for (int q = 0; q < 4; ++q) {
    float p0 = max0P[((size_t)t * 4 + q) * BB + b];
    float p1 = max1P[((size_t)t * 4 + q) * BB + b];
    float n1 = fmaxf(fminf(M0, p0), fmaxf(M1, p1));
    M0 = fmaxf(M0, p0);
    M1 = n1;
  }
  float x0 = M0;
  float x1 = (t == b) ? -INFINITY : M1;
  if (t == b) diag = x0;
  red[t] = fmaxf(x0, x1);
  __syncthreads();
  for (int s = 128; s > 0; s >>= 1) {
    if (t < s) red[t] = fmaxf(red[t], red[t + s]);
    __syncthreads();
  }
  float M = red[0];
  __syncthreads();
  float e = expf(x0 - M) + ((t == b) ? 0.0f : expf(x1 - M));
  red[t] = e;
  __syncthreads();
  for (int s = 128; s > 0; s >>= 1) {
    if (t < s) red[t] = red[t] + red[t + s];
    __syncthreads();
  }
  if (t == 0) lossb[b] = logf(red[0]) + M - diag;
}

__global__ __launch_bounds__(256) void mean_kernel(
    const float* __restrict__ lossb, float* __restrict__ out)
{
  __shared__ float red[256];
  const int t = threadIdx.x;
  red[t] = lossb[t];
  __syncthreads();
  for (int s = 128; s > 0; s >>= 1) {
    if (t < s) red[t] += red[t + s];
    __syncthreads();
  }
  if (t == 0) out[0] = red[0] * (1.0f / 256.0f);
}

extern "C" void kernel_launch(void* const* d_in, const int* in_sizes, int n_in,
                              void* d_out, int out_size, void* d_ws, size_t ws_size,
                              hipStream_t stream) {
  const float* F   = (const float*)d_in[0];   // fusion_fs [256,4096,64] fp32
  const float* lan = (const float*)d_in[1];   // lan_fs    [256,1,64]   fp32
  float* ws = (float*)d_ws;
  float* max0P = ws;                // [256*4*256] = 1 MB
  float* max1P = ws + 262144;       // [256*4*256] = 1 MB
  float* lossb = ws + 524288;       // [256]

  const int shmem = 4 * CHB;        // 32 KB dynamic per block
  hipFuncSetAttribute((const void*)topk_sim_kernel,
                      hipFuncAttributeMaxDynamicSharedMemorySize, shmem);
  topk_sim_kernel<<<1024, 256, shmem, stream>>>(F, lan, max0P, max1P);
  lse_kernel<<<256, 256, 0, stream>>>(max0P, max1P, lossb);
  mean_kernel<<<1, 256, 0, stream>>>(lossb, (float*)d_out);
}